// Round 2
// baseline (408.365 us; speedup 1.0000x reference)
//
#include <hip/hip_runtime.h>
#include <cstdint>
#include <cstddef>

#define NB    32          // batches
#define SEQ   1024        // sequence length
#define DIN   256
#define HID   512
#define MTOT  32768       // NB*SEQ

typedef _Float16 half_t;
typedef _Float16 half8  __attribute__((ext_vector_type(8)));
typedef _Float16 half4v __attribute__((ext_vector_type(4)));
typedef float    f32x4  __attribute__((ext_vector_type(4)));

typedef __attribute__((address_space(1))) const void* gas_ptr;
typedef __attribute__((address_space(3))) void*       las_ptr;

// ---------------- f32 -> f16 convert ----------------
__global__ void cvt_kernel(const float* __restrict__ src, half_t* __restrict__ dst, int n4) {
    int i = blockIdx.x * blockDim.x + threadIdx.x;
    if (i < n4) {
        f32x4 v = ((const f32x4*)src)[i];
        half4v h;
        h[0] = (half_t)v[0]; h[1] = (half_t)v[1]; h[2] = (half_t)v[2]; h[3] = (half_t)v[3];
        ((half4v*)dst)[i] = h;
    }
}

__global__ void cvt4_kernel(const float* __restrict__ s0, const float* __restrict__ s1,
                            const float* __restrict__ s2, const float* __restrict__ s3,
                            half_t* __restrict__ d0, half_t* __restrict__ d1,
                            half_t* __restrict__ d2, half_t* __restrict__ d3, int n4) {
    int y = blockIdx.y;
    const float* s = y == 0 ? s0 : y == 1 ? s1 : y == 2 ? s2 : s3;
    half_t*      d = y == 0 ? d0 : y == 1 ? d1 : y == 2 ? d2 : d3;
    int i = blockIdx.x * blockDim.x + threadIdx.x;
    if (i < n4) {
        f32x4 v = ((const f32x4*)s)[i];
        half4v h;
        h[0] = (half_t)v[0]; h[1] = (half_t)v[1]; h[2] = (half_t)v[2]; h[3] = (half_t)v[3];
        ((half4v*)d)[i] = h;
    }
}

__global__ void pack_bias(const float* __restrict__ bv, const float* __restrict__ bk,
                          const float* __restrict__ bq, float* __restrict__ dst) {
    int t = threadIdx.x;
    if (t < HID) {
        dst[t]         = bv[t];
        dst[HID + t]   = bk[t];
        dst[2*HID + t] = bq[t];
    }
}

// ---------------- generic GEMM (projections), 128x128 tile ----------------
template<int MODE>
__global__ __launch_bounds__(256, 2) void gemm_k(
    const half_t* __restrict__ A, long lda, long a_bs,
    const half_t* __restrict__ Bw, long ldb, long b_bs,
    void* __restrict__ Out, long ldo, long o_bs,
    const float* __restrict__ bias,
    int Kdim, half_t* __restrict__ out2)
{
    __shared__ alignas(16) half_t As[128 * 32];
    __shared__ alignas(16) half_t Bs[128 * 32];

    const int t    = threadIdx.x;
    const int lane = t & 63;
    const int wave = t >> 6;
    const int wm   = wave >> 1;
    const int wn   = wave & 1;
    const int lanen = lane & 15;
    const int quad  = lane >> 4;
    const int z     = blockIdx.z;
    const long m0 = (long)blockIdx.x * 128;
    const long n0 = (long)blockIdx.y * 128;

    const half_t* Ab = A  + (long)z * a_bs;
    const half_t* Bb = Bw + (long)z * b_bs;

    f32x4 acc[4][4];
#pragma unroll
    for (int i = 0; i < 4; i++)
#pragma unroll
        for (int j = 0; j < 4; j++)
            acc[i][j] = f32x4{0.f, 0.f, 0.f, 0.f};

    const int c0 = t, c1 = t + 256;
    const int r0 = c0 >> 2, kc0 = c0 & 3;
    const int r1 = c1 >> 2, kc1 = c1 & 3;

    const half_t* gA0 = Ab + (m0 + r0) * lda + kc0 * 8;
    const half_t* gA1 = Ab + (m0 + r1) * lda + kc1 * 8;
    const half_t* gB0 = Bb + (n0 + r0) * ldb + kc0 * 8;
    const half_t* gB1 = Bb + (n0 + r1) * ldb + kc1 * 8;
    half_t* lA0 = &As[c0 * 8];
    half_t* lA1 = &As[c1 * 8];
    half_t* lB0 = &Bs[c0 * 8];
    half_t* lB1 = &Bs[c1 * 8];

    int aoff[4], boff[4];
#pragma unroll
    for (int i = 0; i < 4; i++) aoff[i] = (wm * 64 + i * 16 + lanen) * 32 + quad * 8;
#pragma unroll
    for (int j = 0; j < 4; j++) boff[j] = (wn * 64 + j * 16 + lanen) * 32 + quad * 8;

    for (int k0 = 0; k0 < Kdim; k0 += 32) {
        __builtin_amdgcn_global_load_lds((gas_ptr)(gA0 + k0), (las_ptr)lA0, 16, 0, 0);
        __builtin_amdgcn_global_load_lds((gas_ptr)(gA1 + k0), (las_ptr)lA1, 16, 0, 0);
        __builtin_amdgcn_global_load_lds((gas_ptr)(gB0 + k0), (las_ptr)lB0, 16, 0, 0);
        __builtin_amdgcn_global_load_lds((gas_ptr)(gB1 + k0), (las_ptr)lB1, 16, 0, 0);
        __syncthreads();

        half8 af[4], bf[4];
#pragma unroll
        for (int i = 0; i < 4; i++) af[i] = *(const half8*)&As[aoff[i]];
#pragma unroll
        for (int j = 0; j < 4; j++) bf[j] = *(const half8*)&Bs[boff[j]];
#pragma unroll
        for (int i = 0; i < 4; i++)
#pragma unroll
            for (int j = 0; j < 4; j++)
                acc[i][j] = __builtin_amdgcn_mfma_f32_16x16x32_f16(af[i], bf[j], acc[i][j], 0, 0, 0);
        __syncthreads();
    }

#pragma unroll
    for (int i = 0; i < 4; i++) {
        long mrow = m0 + wm * 64 + i * 16 + quad * 4;
#pragma unroll
        for (int j = 0; j < 4; j++) {
            long gn = n0 + wn * 64 + j * 16 + lanen;
            f32x4 v = acc[i][j];
            if (MODE == 0) {
                float bb = bias[z * HID + gn];
                half_t h0 = (half_t)fmaxf(v[0] + bb, 0.f);
                half_t h1 = (half_t)fmaxf(v[1] + bb, 0.f);
                half_t h2 = (half_t)fmaxf(v[2] + bb, 0.f);
                half_t h3 = (half_t)fmaxf(v[3] + bb, 0.f);
                if (z == 0) {
                    long bidx = mrow >> 10;
                    long pos  = mrow & 1023;
                    half4v pk; pk[0] = h0; pk[1] = h1; pk[2] = h2; pk[3] = h3;
                    *(half4v*)(out2 + ((bidx * HID + gn) << 10) + pos) = pk;
                } else {
                    half_t* o = (half_t*)Out + (long)(z - 1) * o_bs;
                    o[(mrow + 0) * ldo + gn] = h0;
                    o[(mrow + 1) * ldo + gn] = h1;
                    o[(mrow + 2) * ldo + gn] = h2;
                    o[(mrow + 3) * ldo + gn] = h3;
                }
            } else {
                float* o = (float*)Out;
                float bb = bias[gn];
#pragma unroll
                for (int r = 0; r < 4; r++) o[(mrow + r) * ldo + gn] = fmaxf(v[r] + bb, 0.f);
            }
        }
    }
}

// ---------------- fused flash attention ----------------
// One block = 128 Q rows of one batch. 8 waves (2 q-row-groups x 4 kv/h-groups).
// Loop over 4 KV tiles of 256: S = Q K^T, online softmax (cross-wave stats in LDS),
// P -> LDS (f16, XOR-swizzled), O^T += V^T P^T (operand-swapped MFMA: P is the
// B operand -> contiguous b128 reads). O in registers, normalized + stored at end.
// NOTE: Q and O intentionally alias (in-place) -> no __restrict__ on them.

// staging macros (literal-constant size for global_load_lds; linear LDS dest)
#define STAGE_S(dst, kv0, ho)                                                          \
    do {                                                                               \
        __builtin_amdgcn_global_load_lds((gas_ptr)(Qb + (long)qrow * HID + (ho) + qc * 8), \
                                         (las_ptr)((dst) + t * 8), 16, 0, 0);          \
        half_t* kd_ = (dst) + 4096;                                                    \
        _Pragma("unroll")                                                              \
        for (int s2 = 0; s2 < 2; s2++) {                                               \
            int idx_ = t + 512 * s2;                                                   \
            __builtin_amdgcn_global_load_lds(                                          \
                (gas_ptr)(Kb + (long)((kv0) + (idx_ >> 2)) * HID + (ho) + (idx_ & 3) * 8), \
                (las_ptr)(kd_ + idx_ * 8), 16, 0, 0);                                  \
        }                                                                              \
    } while (0)

#define STAGE_V(dst, kv0, kc)                                                          \
    do {                                                                               \
        _Pragma("unroll")                                                              \
        for (int s2 = 0; s2 < 4; s2++) {                                               \
            int idx_ = t + 512 * s2;                                                   \
            __builtin_amdgcn_global_load_lds(                                          \
                (gas_ptr)(Vb + (long)(idx_ >> 2) * SEQ + (kv0) + (kc) * 32 + (idx_ & 3) * 8), \
                (las_ptr)((dst) + idx_ * 8), 16, 0, 0);                                \
        }                                                                              \
    } while (0)

__global__ __launch_bounds__(512, 2) void flash_k(
    const half_t* Q, const half_t* __restrict__ K,
    const half_t* __restrict__ vT, half_t* O)
{
    // LDS map (137216 B):
    //  [0,64K):   union: sbuf0=[0,24K) sbuf1=[40K,64K)  (Q 8K + K 16K each)
    //             vbufA=[0,32K) vbufB=[32K,64K)         (vT chunk 512x32)
    //  [64K,128K): Ps 128x256 f16 (swizzled)
    //  [128K,..):  stats: m_s,l_s,al_s,mn_s (128 f32 each), pm[128][4], psum[128][4]
    __shared__ alignas(16) unsigned char SM[137216];
    half_t* Uh   = (half_t*)SM;
    half_t* Ps   = (half_t*)(SM + 65536);
    float*  m_s  = (float*)(SM + 131072);
    float*  l_s  = (float*)(SM + 131072 + 512);
    float*  al_s = (float*)(SM + 131072 + 1024);
    float*  mn_s = (float*)(SM + 131072 + 1536);
    float*  pm   = (float*)(SM + 131072 + 2048);
    float*  psum = (float*)(SM + 131072 + 4096);

    half_t* sb[2] = { Uh, Uh + 20480 };        // 24KB each
    half_t* vb[2] = { Uh, Uh + 16384 };        // 32KB each

    const int t     = threadIdx.x;
    const int lane  = t & 63;
    const int wv    = t >> 6;       // 0..7
    const int wA    = wv & 1;       // q-row group (64 rows)
    const int wB    = wv >> 1;      // S col group (64 cols) / PV h group (128 cols)
    const int lanen = lane & 15;
    const int quad  = lane >> 4;

    // XCD swizzle: batch z's 8 m-blocks land on XCD (z&7)
    const int bid = blockIdx.x;
    const int z   = (bid & 7) + 8 * ((bid >> 3) & 3);
    const long m0 = (long)(bid >> 5) * 128;

    const half_t* Qb = Q  + (long)z * SEQ * HID + m0 * HID;
    const half_t* Kb = K  + (long)z * SEQ * HID;
    const half_t* Vb = vT + (long)z * HID * SEQ;
    half_t*       Ob = O  + (long)z * SEQ * HID + m0 * HID;

    const int qrow = t >> 2, qc = t & 3;

    if (t < 128) { m_s[t] = -1e30f; l_s[t] = 0.f; }

    // O^T accumulators: acc2[a][b]: row(h) = wB*128+a*16+quad*4+rr, col(q) = wA*64+b*16+lanen
    f32x4 acc2[8][4];
#pragma unroll
    for (int a = 0; a < 8; a++)
#pragma unroll
        for (int b = 0; b < 4; b++) acc2[a][b] = f32x4{0.f,0.f,0.f,0.f};

    // Ps swizzle: byte ^= ((q&3)<<4) ^ (((q>>2)&3)<<5)
    const int pswz_r = ((lanen & 3) << 4) ^ (((lanen >> 2) & 3) << 5);   // read side (q=..+lanen)
    const int wmaskq = quad << 5;                                        // write side ((q>>2)&3 = quad)

    STAGE_S(sb[0], 0, 0);
    __syncthreads();

    for (int kt = 0; kt < 4; kt++) {
        const int kv0 = kt * 256;

        // ---- S phase: 16 hid-chunks of 32, double-buffered ----
        f32x4 acc[4][4];
#pragma unroll
        for (int i = 0; i < 4; i++)
#pragma unroll
            for (int jj = 0; jj < 4; jj++) acc[i][jj] = f32x4{0.f,0.f,0.f,0.f};

        for (int c = 0; c < 16; c++) {
            if (c < 15) STAGE_S(sb[(c + 1) & 1], kv0, (c + 1) * 32);
            else        STAGE_V(vb[0], kv0, 0);          // prefetch vT chunk 0 under stats
            const half_t* Qc = sb[c & 1];
            const half_t* Kc = sb[c & 1] + 4096;
            half8 bf[4];
#pragma unroll
            for (int jj = 0; jj < 4; jj++)
                bf[jj] = *(const half8*)&Kc[(wB * 64 + jj * 16 + lanen) * 32 + quad * 8];
#pragma unroll
            for (int i = 0; i < 4; i++) {
                half8 af = *(const half8*)&Qc[(wA * 64 + i * 16 + lanen) * 32 + quad * 8];
#pragma unroll
                for (int jj = 0; jj < 4; jj++)
                    acc[i][jj] = __builtin_amdgcn_mfma_f32_16x16x32_f16(af, bf[jj], acc[i][jj], 0, 0, 0);
            }
            __syncthreads();
        }

        // ---- stats: partial row-max per wave -> LDS -> merge ----
#pragma unroll
        for (int i = 0; i < 4; i++) {
            float px[4];
#pragma unroll
            for (int rr = 0; rr < 4; rr++) {
                float v = fmaxf(fmaxf(acc[i][0][rr], acc[i][1][rr]),
                                fmaxf(acc[i][2][rr], acc[i][3][rr]));
                v = fmaxf(v, __shfl_xor(v, 1, 64));
                v = fmaxf(v, __shfl_xor(v, 2, 64));
                v = fmaxf(v, __shfl_xor(v, 4, 64));
                v = fmaxf(v, __shfl_xor(v, 8, 64));
                px[rr] = v;
            }
            if (lanen == 0) {
#pragma unroll
                for (int rr = 0; rr < 4; rr++)
                    pm[(wA * 64 + i * 16 + quad * 4 + rr) * 4 + wB] = px[rr];
            }
        }
        __syncthreads();

        // ---- merge max, exp, write P, partial sums ----
#pragma unroll
        for (int i = 0; i < 4; i++) {
            float mn_[4], al_[4], sm_[4];
#pragma unroll
            for (int rr = 0; rr < 4; rr++) {
                int row = wA * 64 + i * 16 + quad * 4 + rr;
                f32x4 p4 = *(const f32x4*)&pm[row * 4];
                float tm = fmaxf(fmaxf(p4[0], p4[1]), fmaxf(p4[2], p4[3]));
                float mo = m_s[row];
                float mn = fmaxf(mo, tm);
                mn_[rr] = mn;
                al_[rr] = __expf(mo - mn);
                sm_[rr] = 0.f;
            }
#pragma unroll
            for (int jj = 0; jj < 4; jj++) {
                int col = wB * 64 + jj * 16 + lanen;
#pragma unroll
                for (int rr = 0; rr < 4; rr++) {
                    float e = __expf(acc[i][jj][rr] - mn_[rr]);
                    sm_[rr] += e;
                    int q = wA * 64 + i * 16 + quad * 4 + rr;
                    int byteoff = q * 512 + ((col * 2) ^ (rr << 4) ^ wmaskq);
                    *(half_t*)((unsigned char*)Ps + byteoff) = (half_t)e;
                }
            }
#pragma unroll
            for (int rr = 0; rr < 4; rr++) {
                float v = sm_[rr];
                v += __shfl_xor(v, 1, 64);
                v += __shfl_xor(v, 2, 64);
                v += __shfl_xor(v, 4, 64);
                v += __shfl_xor(v, 8, 64);
                sm_[rr] = v;
            }
            if (lanen == 0) {
#pragma unroll
                for (int rr = 0; rr < 4; rr++) {
                    int row = wA * 64 + i * 16 + quad * 4 + rr;
                    psum[row * 4 + wB] = sm_[rr];
                    if (wB == 0) { al_s[row] = al_[rr]; mn_s[row] = mn_[rr]; }
                }
            }
        }
        __syncthreads();

        // finalize running stats (waves wv0/wv1, lanen==0); l_s/m_s not read until after
        // later barriers (epilogue / next tile's merge), so no extra barrier needed.
        if (wB == 0 && lanen == 0) {
#pragma unroll
            for (int i = 0; i < 4; i++)
#pragma unroll
                for (int rr = 0; rr < 4; rr++) {
                    int row = wA * 64 + i * 16 + quad * 4 + rr;
                    f32x4 s4 = *(const f32x4*)&psum[row * 4];
                    l_s[row] = l_s[row] * al_s[row] + (s4[0] + s4[1] + s4[2] + s4[3]);
                    m_s[row] = mn_s[row];
                }
        }

        // rescale O accumulator by alpha (per q column)
#pragma unroll
        for (int b = 0; b < 4; b++) {
            float al = al_s[wA * 64 + b * 16 + lanen];
#pragma unroll
            for (int a = 0; a < 8; a++) {
                acc2[a][b][0] *= al; acc2[a][b][1] *= al;
                acc2[a][b][2] *= al; acc2[a][b][3] *= al;
            }
        }

        // ---- PV phase: 8 kv-subchunks of 32, double-buffered; O^T = V^T P^T ----
        for (int kc = 0; kc < 8; kc++) {
            if (kc < 7)      STAGE_V(vb[(kc + 1) & 1], kv0, kc + 1);
            else if (kt < 3) STAGE_S(sb[0], kv0 + 256, 0);   // prefetch next K-tile's chunk 0
            const half_t* Vc = vb[kc & 1];
            half8 pf[4];
#pragma unroll
            for (int b = 0; b < 4; b++) {
                int q = wA * 64 + b * 16 + lanen;
                int byteoff = q * 512 + ((kc * 64 + quad * 16) ^ pswz_r);
                pf[b] = *(const half8*)((const unsigned char*)Ps + byteoff);
            }
#pragma unroll
            for (int a = 0; a < 8; a++) {
                half8 vf = *(const half8*)&Vc[(wB * 128 + a * 16 + lanen) * 32 + quad * 8];
#pragma unroll
                for (int b = 0; b < 4; b++)
                    acc2[a][b] = __builtin_amdgcn_mfma_f32_16x16x32_f16(vf, pf[b], acc2[a][b], 0, 0, 0);
            }
            __syncthreads();
        }
    }

    // ---- epilogue: normalize, f16, store (8B per store: 4 consecutive h) ----
#pragma unroll
    for (int b = 0; b < 4; b++) {
        long qg = wA * 64 + b * 16 + lanen;
        float inv = 1.f / l_s[qg];
#pragma unroll
        for (int a = 0; a < 8; a++) {
            f32x4 v = acc2[a][b];
            half4v pk;
            pk[0] = (half_t)(v[0] * inv); pk[1] = (half_t)(v[1] * inv);
            pk[2] = (half_t)(v[2] * inv); pk[3] = (half_t)(v[3] * inv);
            *(half4v*)&Ob[qg * HID + wB * 128 + a * 16 + quad * 4] = pk;
        }
    }
}

// ---------------- host ----------------
extern "C" void kernel_launch(void* const* d_in, const int* in_sizes, int n_in,
                              void* d_out, int out_size, void* d_ws, size_t ws_size,
                              hipStream_t stream) {
    const float* h  = (const float*)d_in[0];
    const float* Wv = (const float*)d_in[1];
    const float* bv = (const float*)d_in[2];
    const float* Wk = (const float*)d_in[3];
    const float* bk = (const float*)d_in[4];
    const float* Wq = (const float*)d_in[5];
    const float* bq = (const float*)d_in[6];
    const float* Wo = (const float*)d_in[7];
    const float* bo = (const float*)d_in[8];

    uint8_t* ws = (uint8_t*)d_ws;
    size_t off = 0;
    auto alloc = [&](size_t bytes) { size_t o = off; off += (bytes + 255) & ~(size_t)255; return o; };

    half_t* W16   = (half_t*)(ws + alloc((size_t)3 * HID * DIN * 2)); // [Wv][Wk][Wq]
    half_t* Wo16  = (half_t*)(ws + alloc((size_t)DIN * HID * 2));
    float*  biasq = (float*)(ws + alloc((size_t)3 * HID * 4));        // [bv][bk][bq]
    half_t* k16   = (half_t*)(ws + alloc((size_t)MTOT * HID * 2));
    half_t* q16   = (half_t*)(ws + alloc((size_t)MTOT * HID * 2));    // Q; overwritten in-place by O
    half_t* vT    = (half_t*)(ws + alloc((size_t)MTOT * HID * 2));    // [b][h][m]
    half_t* h16   = (half_t*)(ws + alloc((size_t)MTOT * DIN * 2));

    // K0: conversions
    cvt_kernel<<<dim3((MTOT * DIN / 4 + 255) / 256), 256, 0, stream>>>(h, h16, MTOT * DIN / 4);
    cvt4_kernel<<<dim3((HID * DIN / 4 + 255) / 256, 4), 256, 0, stream>>>(
        Wv, Wk, Wq, Wo, W16, W16 + HID * DIN, W16 + 2 * HID * DIN, Wo16, HID * DIN / 4);
    pack_bias<<<dim3(1), 512, 0, stream>>>(bv, bk, bq, biasq);

    // K1: QKV projections (z: 0=V->vT, 1=K, 2=Q)
    gemm_k<0><<<dim3(MTOT / 128, HID / 128, 3), 256, 0, stream>>>(
        h16, DIN, 0,
        W16, DIN, (long)HID * DIN,
        (void*)k16, HID, (long)MTOT * HID,
        biasq, DIN, vT);

    // K2: fused flash attention (writes O in place of Q — each block only touches its own rows)
    flash_k<<<dim3(NB * (SEQ / 128)), dim3(512), 0, stream>>>(q16, k16, vT, q16);

    // K3: out = relu(O Wo^T + bo)  (f32 out)
    gemm_k<3><<<dim3(MTOT / 128, DIN / 128, 1), 256, 0, stream>>>(
        q16, HID, 0,
        Wo16, HID, 0,
        d_out, DIN, 0,
        bo, HID, nullptr);

    (void)in_sizes; (void)n_in; (void)out_size; (void)ws_size;
}